// Round 7
// baseline (208.400 us; speedup 1.0000x reference)
//
#include <hip/hip_runtime.h>
#include <cstdint>
#include <cstddef>

#define NA 8400   // anchors per image: 80*80 + 40*40 + 20*20
#define NAP 8448  // padded stride (33*256)
#define NB 32     // batch
#define NG 20     // ground truths per image
#define NCL 80    // classes
#define NBLK 33   // 256-thread blocks per image

// ---------- fast math ----------
__device__ __forceinline__ float frcp(float x) { return __builtin_amdgcn_rcpf(x); }
__device__ __forceinline__ float bce0(float x) {
  return fmaxf(x, 0.0f) + __logf(1.0f + __expf(-fabsf(x)));
}

__device__ __forceinline__ void anchor_info(int a, const float* p8, const float* p16,
                                            const float* p32, int b, const float*& base,
                                            int& hw, int& HW, int& xg, int& yg, float& fs) {
  if (a < 6400)      { hw = a;        HW = 6400; xg = hw % 80; yg = hw / 80; fs = 8.f;
                       base = p8  + (size_t)b * 85 * 6400; }
  else if (a < 8000) { hw = a - 6400; HW = 1600; xg = hw % 40; yg = hw / 40; fs = 16.f;
                       base = p16 + (size_t)b * 85 * 1600; }
  else               { hw = a - 8000; HW = 400;  xg = hw % 20; yg = hw / 20; fs = 32.f;
                       base = p32 + (size_t)b * 85 * 400; }
}

__device__ __forceinline__ float iou_raw(float gx, float gy, float gw, float gh, float4 p) {
  float gtlx = gx - gw * 0.5f, gtly = gy - gh * 0.5f;
  float gbrx = gx + gw * 0.5f, gbry = gy + gh * 0.5f;
  float ptlx = p.x - p.z * 0.5f, ptly = p.y - p.w * 0.5f;
  float pbrx = p.x + p.z * 0.5f, pbry = p.y + p.w * 0.5f;
  float tlx = fmaxf(gtlx, ptlx), tly = fmaxf(gtly, ptly);
  float brx = fminf(gbrx, pbrx), bry = fminf(gbry, pbry);
  float inter = ((tlx < brx) && (tly < bry)) ? (brx - tlx) * (bry - tly) : 0.0f;
  float ag = gw * gh, ap = p.z * p.w;
  return inter * frcp(ag + ap - inter + 1e-16f);
}

// cost from staged class logit x — identical instruction chain everywhere.
__device__ __forceinline__ float cost_from_x(float x, float lso, float slr,
                                             unsigned int am, int g,
                                             float gx, float gy, float gw, float gh,
                                             float4 pb, float& iou_out) {
  float u = __logf(1.0f + __expf(-fabsf(x)));
  float lsx = fminf(x, 0.0f) - u;
  float lpr = 0.5f * (lsx + lso);
  float p   = __expf(lpr);
  float l1p = fmaxf(__logf(1.0f - p), -100.0f);
  float wv  = fmaxf(lpr, -100.0f) - l1p;          // lp - l1p
  float iou = iou_raw(gx, gy, gw, gh, pb);
  iou_out = iou;
  float cst = -(wv + slr) - 3.0f * __logf(iou + 1e-8f);
  if (!((am >> g) & 1u)) cst += 100000.0f;
  return cst;
}

__device__ __forceinline__ float giou_loss(float4 bb, float gx, float gy, float gw, float gh) {
  float btlx = bb.x - bb.z * 0.5f, btly = bb.y - bb.w * 0.5f;
  float bbrx = bb.x + bb.z * 0.5f, bbry = bb.y + bb.w * 0.5f;
  float gtlx = gx - gw * 0.5f, gtly = gy - gh * 0.5f;
  float gbrx = gx + gw * 0.5f, gbry = gy + gh * 0.5f;
  float tlx = fmaxf(btlx, gtlx), tly = fmaxf(btly, gtly);
  float brx = fminf(bbrx, gbrx), bry = fminf(bbry, gbry);
  float area_b = bb.z * bb.w, area_g = gw * gh;
  float inter = ((tlx < brx) && (tly < bry)) ? (brx - tlx) * (bry - tly) : 0.0f;
  float uni = area_b + area_g - inter;
  float iou = inter / (uni + 1e-16f);
  float ctlx = fminf(btlx, gtlx), ctly = fminf(btly, gtly);
  float cbrx = fmaxf(bbrx, gbrx), cbry = fmaxf(bbry, gbry);
  float area_c = fmaxf((cbrx - ctlx) * (cbry - ctly), 1e-16f);
  float giou = iou - (area_c - uni) / area_c;
  giou = fminf(fmaxf(giou, -1.0f), 1.0f);
  return 1.0f - giou;
}

// ---------- kA: geometry + compaction + decode + obj-BCE + dense class sums
//              + staged gt-class logits (all coalesced, no 8-part machinery) ----------
__global__ __launch_bounds__(256) void kA(const float* __restrict__ p8,
                                          const float* __restrict__ p16,
                                          const float* __restrict__ p32,
                                          const float* __restrict__ labels,
                                          int* __restrict__ n_fg_cnt,
                                          float4* __restrict__ meta_c,
                                          float4* __restrict__ bbox_c,
                                          float* __restrict__ sb_c,
                                          float* __restrict__ x_tbl,
                                          unsigned int* __restrict__ match_c,
                                          float* __restrict__ blk_obj) {
  __shared__ float s_gt[NG * 4];
  __shared__ int   s_gcls[NG];
  __shared__ unsigned int s_wcnt[4];
  __shared__ float s_part[4];
  __shared__ unsigned int s_base;

  int blk = blockIdx.x, b = blockIdx.y, tid = threadIdx.x, lane = tid & 63, wid = tid >> 6;
  size_t bo = (size_t)b * NAP;

  if (tid < NG) {
    s_gt[tid * 4 + 0] = labels[((size_t)b * NG + tid) * 5 + 0];
    s_gt[tid * 4 + 1] = labels[((size_t)b * NG + tid) * 5 + 1];
    s_gt[tid * 4 + 2] = labels[((size_t)b * NG + tid) * 5 + 2];
    s_gt[tid * 4 + 3] = labels[((size_t)b * NG + tid) * 5 + 3];
    s_gcls[tid] = (int)labels[((size_t)b * NG + tid) * 5 + 4];
  }
  __syncthreads();

  // ---- phase 1: fg test ----
  int a = blk * 256 + tid;
  match_c[bo + a] = 0u;                  // NBLK*256 == NAP: full coverage
  bool fg = false;
  unsigned int msk = 0u;
  float bce_obj = 0.0f, obj = 0.0f;
  const float* base = nullptr; int hw = 0, HW = 0, xg = 0, yg = 0; float fs = 8.f;
  if (a < NA) {
    anchor_info(a, p8, p16, p32, b, base, hw, HW, xg, yg, fs);
    obj = base[4 * HW + hw];             // coalesced obj-plane stream
    bce_obj = bce0(obj);
    float xc = ((float)xg + 0.5f) * fs;
    float yc = ((float)yg + 0.5f) * fs;
    float r = 2.5f * fs;
#pragma unroll
    for (int g = 0; g < NG; ++g) {
      float gx = s_gt[g * 4 + 0], gy = s_gt[g * 4 + 1];
      float gw = s_gt[g * 4 + 2], gh = s_gt[g * 4 + 3];
      bool inb = (xc > gx - 0.5f * gw) && (xc < gx + 0.5f * gw) &&
                 (yc > gy - 0.5f * gh) && (yc < gy + 0.5f * gh);
      bool inc = (xc > gx - r) && (xc < gx + r) && (yc > gy - r) && (yc < gy + r);
      fg = fg || inb || inc;
      if (inb && inc) msk |= (1u << g);
    }
  }

  unsigned long long bm = __ballot(fg);
#pragma unroll
  for (int off = 32; off; off >>= 1) bce_obj += __shfl_down(bce_obj, off, 64);
  if (lane == 0) { s_wcnt[wid] = (unsigned int)__popcll(bm); s_part[wid] = bce_obj; }
  __syncthreads();
  if (tid == 0) {
    unsigned int cnt = s_wcnt[0] + s_wcnt[1] + s_wcnt[2] + s_wcnt[3];
    s_base = cnt ? (unsigned int)atomicAdd(&n_fg_cnt[b], (int)cnt) : 0u;
    blk_obj[b * NBLK + blk] = s_part[0] + s_part[1] + s_part[2] + s_part[3];
  }
  __syncthreads();

  if (!fg) return;   // all remaining work is per-fg-thread

  unsigned int li = 0;
  for (int w = 0; w < wid; ++w) li += s_wcnt[w];
  li += (unsigned int)__popcll(bm & ((1ull << lane) - 1ull));
  int ci = (int)(s_base + li);

  // decode bbox + lso
  float v0 = base[hw];
  float v1 = base[HW + hw];
  float v2 = base[2 * HW + hw];
  float v3 = base[3 * HW + hw];
  float4 bb4 = make_float4((v0 + (float)xg) * fs, (v1 + (float)yg) * fs,
                           __expf(v2) * fs, __expf(v3) * fs);
  float uo = __logf(1.0f + __expf(-fabsf(obj)));
  float lso = fminf(obj, 0.0f) - uo;     // log(sigmoid(obj))

  // dense class sweep c = 0..79 (same FP order as old 8x10 scheme -> identical bits)
  float sb = 0.0f, sl = 0.0f;
  const float* cb = base + (size_t)5 * HW + hw;
  for (int c = 0; c < NCL; ++c) {
    float x = cb[(size_t)c * HW];        // coalesced across lanes (consecutive hw)
    float u = __logf(1.0f + __expf(-fabsf(x)));
    sb += fmaxf(x, 0.0f) + u;            // bce(x,0)
    float lsx = fminf(x, 0.0f) - u;      // log(sigmoid(x))
    float lpr = 0.5f * (lsx + lso);      // log p
    float p   = __expf(lpr);
    sl += fmaxf(__logf(1.0f - p), -100.0f);
  }

  // stage the 20 gt-class logits (fixed class per g -> coalesced, L2/L3-hot)
#pragma unroll
  for (int g = 0; g < NG; ++g) {
    float xgl = base[(size_t)(5 + s_gcls[g]) * HW + hw];
    x_tbl[((size_t)b * NG + g) * NAP + ci] = xgl;
  }

  bbox_c[bo + ci] = bb4;
  sb_c[bo + ci] = sb;
  meta_c[bo + ci] = make_float4(lso, sl, __uint_as_float(msk), obj);
}

// ---------- kBG: per-(b,g) packed-stream cost/iou + single-pass top-k + mark,
//             then per-image ticket finalize + final-scalar ticket ----------
__global__ __launch_bounds__(256) void kBG(const float* __restrict__ labels,
                                           const int* __restrict__ n_fg,
                                           const float4* __restrict__ meta_c,
                                           const float4* __restrict__ bbox_c,
                                           const float* __restrict__ sb_c,
                                           const float* __restrict__ x_tbl,
                                           unsigned int* __restrict__ match_c,
                                           const float* __restrict__ blk_obj,
                                           float* __restrict__ accum,
                                           int* __restrict__ done_g,
                                           int* __restrict__ done_img,
                                           float* __restrict__ out) {
  __shared__ float s_gt[NG * 5];
  __shared__ float s_wt[4 * 10];
  __shared__ float s_wc[4 * 10];
  __shared__ int   s_wi[4 * 10];
  __shared__ float s_red[16];
  __shared__ int   s_flag;

  int g = blockIdx.x, b = blockIdx.y, tid = threadIdx.x;
  int lane = tid & 63, wid = tid >> 6;
  int n = n_fg[b];
  size_t bo = (size_t)b * NAP;
  const float* __restrict__ xrow = x_tbl + ((size_t)b * NG + g) * NAP;

  if (tid < NG * 5) s_gt[tid] = labels[(size_t)b * NG * 5 + tid];
  __syncthreads();

  float ggx = s_gt[g * 5], ggy = s_gt[g * 5 + 1];
  float ggw = s_gt[g * 5 + 2], ggh = s_gt[g * 5 + 3];

  float t10[10];          // top-10 ious (descending)
  float c10v[10];         // top-10 smallest costs (ascending)
  int   c10i[10];
#pragma unroll
  for (int j = 0; j < 10; ++j) { t10[j] = 0.0f; c10v[j] = 3.4e38f; c10i[j] = 0x7fffffff; }

  for (int ci = tid; ci < n; ci += 256) {
    float4 me = meta_c[bo + ci];
    float4 pb = bbox_c[bo + ci];
    float x = xrow[ci];
    unsigned int am = __float_as_uint(me.z);
    float iou;
    float cst = cost_from_x(x, me.x, me.y, am, g, ggx, ggy, ggw, ggh, pb, iou);
    if (iou > t10[9]) {
      t10[9] = iou;
#pragma unroll
      for (int q = 9; q > 0; --q) {
        if (t10[q] > t10[q - 1]) { float t = t10[q]; t10[q] = t10[q - 1]; t10[q - 1] = t; }
        else break;
      }
    }
    if (cst < c10v[9] || (cst == c10v[9] && ci < c10i[9])) {
      c10v[9] = cst; c10i[9] = ci;
#pragma unroll
      for (int q = 9; q > 0; --q) {
        if (c10v[q] < c10v[q - 1] ||
            (c10v[q] == c10v[q - 1] && c10i[q] < c10i[q - 1])) {
          float tv = c10v[q]; c10v[q] = c10v[q - 1]; c10v[q - 1] = tv;
          int   ti = c10i[q]; c10i[q] = c10i[q - 1]; c10i[q - 1] = ti;
        } else break;
      }
    }
  }

  // per-wave extraction: 10 rounds; iou-max and cost-min chains interleaved (ILP)
  for (int r = 0; r < 10; ++r) {
    float v = t10[0];
    float bv = v;
    float cv = c10v[0]; int cix = c10i[0];
    float cbv = cv;     int cbi = cix;
#pragma unroll
    for (int off = 32; off; off >>= 1) {
      bv = fmaxf(bv, __shfl_down(bv, off, 64));
      float ov = __shfl_down(cbv, off, 64);
      int   oi = __shfl_down(cbi, off, 64);
      if (ov < cbv || (ov == cbv && oi < cbi)) { cbv = ov; cbi = oi; }
    }
    bv  = __shfl(bv, 0, 64);
    cbv = __shfl(cbv, 0, 64);
    cbi = __shfl(cbi, 0, 64);
    unsigned long long won = __ballot(v == bv);
    if (lane == __ffsll(won) - 1) {
#pragma unroll
      for (int q = 0; q < 9; ++q) t10[q] = t10[q + 1];
      t10[9] = -1.0f;
    }
    if (cv == cbv && cix == cbi) {       // unique owner (ci unique within block)
#pragma unroll
      for (int q = 0; q < 9; ++q) { c10v[q] = c10v[q + 1]; c10i[q] = c10i[q + 1]; }
      c10v[9] = 3.4e38f; c10i[9] = 0x7fffffff;
    }
    if (lane == 0) {
      s_wt[wid * 10 + r] = bv;
      s_wc[wid * 10 + r] = cbv;
      s_wi[wid * 10 + r] = cbi;
    }
  }
  __syncthreads();

  if (tid == 0) {
    // merge 4 sorted desc iou lists -> dyn_k (sum in desc order, trunc, clip 1)
    int p0 = 0, p1 = 0, p2 = 0, p3 = 0;
    float s = 0.0f;
    for (int r = 0; r < 10; ++r) {
      float v0 = (p0 < 10) ? s_wt[p0]      : -2.0f;
      float v1 = (p1 < 10) ? s_wt[10 + p1] : -2.0f;
      float v2 = (p2 < 10) ? s_wt[20 + p2] : -2.0f;
      float v3 = (p3 < 10) ? s_wt[30 + p3] : -2.0f;
      float m = fmaxf(fmaxf(v0, v1), fmaxf(v2, v3));
      s += m;
      if (m == v0) ++p0; else if (m == v1) ++p1; else if (m == v2) ++p2; else ++p3;
    }
    int k = (int)s;
    if (k < 1) k = 1;
    // merge 4 sorted asc (cost,ci) lists -> mark k smallest
    int q[4] = {0, 0, 0, 0};
    for (int it = 0; it < k; ++it) {
      float bv = 3.3e38f; int bi = 0x7fffffff; int sel = -1;
#pragma unroll
      for (int w = 0; w < 4; ++w) {
        if (q[w] < 10) {
          float v = s_wc[w * 10 + q[w]];
          int   i = s_wi[w * 10 + q[w]];
          if (v < bv || (v == bv && i < bi)) { bv = v; bi = i; sel = w; }
        }
      }
      if (sel < 0 || bv >= 1e37f) break;   // exhausted real candidates
      atomicOr(&match_c[bo + bi], 1u << g);
      ++q[sel];
    }
    // per-image ticket
    __threadfence();
    s_flag = (atomicAdd(&done_g[b], 1) == NG - 1) ? 1 : 0;
  }
  __syncthreads();
  if (!s_flag) return;

  // ---- finalize (winner block of image b) — packed tables only, no gathers ----
  float li = 0.0f, oe = 0.0f, lc = 0.0f, nf = 0.0f;
  for (int ci = tid; ci < n; ci += 256) {
    unsigned int m = atomicOr(&match_c[bo + ci], 0u);   // coherence-point read
    if (m == 0u) continue;
    float4 me = meta_c[bo + ci];
    float4 pb = bbox_c[bo + ci];
    unsigned int am = __float_as_uint(me.z);
    int mg;
    if (m & (m - 1)) {
      float bestc = 3.4e38f; mg = 0;
      for (int gq = 0; gq < NG; ++gq) {
        float xq = x_tbl[((size_t)b * NG + gq) * NAP + ci];
        float iouq;
        float cq = cost_from_x(xq, me.x, me.y, am, gq, s_gt[gq * 5], s_gt[gq * 5 + 1],
                               s_gt[gq * 5 + 2], s_gt[gq * 5 + 3], pb, iouq);
        if (cq < bestc) { bestc = cq; mg = gq; }
      }
    } else {
      mg = __ffs(m) - 1;
    }
    float gx = s_gt[mg * 5], gy = s_gt[mg * 5 + 1];
    float gw = s_gt[mg * 5 + 2], gh = s_gt[mg * 5 + 3];
    float piou = iou_raw(gx, gy, gw, gh, pb);
    li += giou_loss(pb, gx, gy, gw, gh);
    float xcls = x_tbl[((size_t)b * NG + mg) * NAP + ci];
    lc += sb_c[bo + ci] - xcls * piou;   // bce(x,t) = bce(x,0) - x*t
    oe += me.w;                          // obj logit: bce(x,1) = bce(x,0) - x
    nf += 1.0f;
  }

  float vals[4] = {li, oe, lc, nf};
#pragma unroll
  for (int q2 = 0; q2 < 4; ++q2) {
#pragma unroll
    for (int off = 32; off; off >>= 1) vals[q2] += __shfl_down(vals[q2], off, 64);
  }
  if (lane == 0) {
    s_red[wid * 4 + 0] = vals[0];
    s_red[wid * 4 + 1] = vals[1];
    s_red[wid * 4 + 2] = vals[2];
    s_red[wid * 4 + 3] = vals[3];
  }
  __syncthreads();
  if (tid < 4) {
    const int slot[4] = {0, 2, 3, 4};
    float s = s_red[tid] + s_red[4 + tid] + s_red[8 + tid] + s_red[12 + tid];
    atomicAdd(&accum[slot[tid]], s);
  }

  // ---- final ticket: last image's finalize block emits the scalar ----
  if (tid == 0) {
    __threadfence();
    s_flag = (atomicAdd(done_img, 1) == NB - 1) ? 1 : 0;
  }
  __syncthreads();
  if (!s_flag) return;

  float s = 0.0f;
  for (int i = tid; i < NB * NBLK; i += 256) s += blk_obj[i];  // obj-BCE base
#pragma unroll
  for (int off = 32; off; off >>= 1) s += __shfl_down(s, off, 64);
  if ((tid & 63) == 0) s_red[tid >> 6] = s;
  __syncthreads();
  if (tid == 0) {
    float obj_base = s_red[0] + s_red[1] + s_red[2] + s_red[3];
    float loss_iou = atomicAdd(&accum[0], 0.0f);   // coherent read-backs
    float oex      = atomicAdd(&accum[2], 0.0f);
    float loss_cls = atomicAdd(&accum[3], 0.0f);
    float num_fg   = atomicAdd(&accum[4], 0.0f);
    float loss_obj = obj_base - oex;
    out[0] = (5.0f * loss_iou + loss_obj + loss_cls) / fmaxf(num_fg, 1.0f);
  }
}

// ---------- launch ----------
extern "C" void kernel_launch(void* const* d_in, const int* in_sizes, int n_in,
                              void* d_out, int out_size, void* d_ws, size_t ws_size,
                              hipStream_t stream) {
  const float* p8     = (const float*)d_in[0];
  const float* p16    = (const float*)d_in[1];
  const float* p32    = (const float*)d_in[2];
  const float* labels = (const float*)d_in[3];
  float* out = (float*)d_out;

  const size_t BAP = (size_t)NB * NAP;     // 270336
  char* w = (char*)d_ws;
  float4*       bbox_c   = (float4*)w;                             // 4.33 MB, 16B-aligned
  float4*       meta_c   = (float4*)(w + BAP * 16);                // 4.33 MB
  float*        x_tbl    = (float*)(w + BAP * 32);                 // NB*NG*NAP*4 = 21.6 MB
  char*         w2       = (char*)x_tbl + (size_t)NB * NG * NAP * 4;
  float*        sb_c     = (float*)(w2);
  unsigned int* match_c  = (unsigned int*)(w2 + BAP * 4);
  char*         w3       = w2 + BAP * 8;
  // zeroed region (512 B): n_fg(32i)@0, accum(8f)@128, done_g(32i)@256, done_img@384
  int*          n_fg     = (int*)w3;
  float*        accum    = (float*)(w3 + 128);
  int*          done_g   = (int*)(w3 + 256);
  int*          done_img = (int*)(w3 + 384);
  float*        blk_obj  = (float*)(w3 + 512);                     // NB*NBLK floats (4224 B)

  hipMemsetAsync(w3, 0, 512, stream);

  kA <<<dim3(NBLK, NB), dim3(256), 0, stream>>>(p8, p16, p32, labels, n_fg, meta_c,
                                                bbox_c, sb_c, x_tbl, match_c, blk_obj);
  kBG<<<dim3(NG, NB), dim3(256), 0, stream>>>(labels, n_fg, meta_c, bbox_c, sb_c, x_tbl,
                                              match_c, blk_obj, accum, done_g,
                                              done_img, out);
}

// Round 8
// 199.952 us; speedup vs baseline: 1.0422x; 1.0422x over previous
//
#include <hip/hip_runtime.h>
#include <cstdint>
#include <cstddef>

#define NA 8400   // anchors per image: 80*80 + 40*40 + 20*20
#define NAP 8448  // padded stride (33*256)
#define NB 32     // batch
#define NG 20     // ground truths per image
#define NCL 80    // classes
#define NBLK 33   // 256-thread blocks per image

// ---------- fast math ----------
__device__ __forceinline__ float frcp(float x) { return __builtin_amdgcn_rcpf(x); }
__device__ __forceinline__ float bce0(float x) {
  return fmaxf(x, 0.0f) + __logf(1.0f + __expf(-fabsf(x)));
}

__device__ __forceinline__ void anchor_info(int a, const float* p8, const float* p16,
                                            const float* p32, int b, const float*& base,
                                            int& hw, int& HW, int& xg, int& yg, float& fs) {
  if (a < 6400)      { hw = a;        HW = 6400; xg = hw % 80; yg = hw / 80; fs = 8.f;
                       base = p8  + (size_t)b * 85 * 6400; }
  else if (a < 8000) { hw = a - 6400; HW = 1600; xg = hw % 40; yg = hw / 40; fs = 16.f;
                       base = p16 + (size_t)b * 85 * 1600; }
  else               { hw = a - 8000; HW = 400;  xg = hw % 20; yg = hw / 20; fs = 32.f;
                       base = p32 + (size_t)b * 85 * 400; }
}

__device__ __forceinline__ float iou_raw(float gx, float gy, float gw, float gh, float4 p) {
  float gtlx = gx - gw * 0.5f, gtly = gy - gh * 0.5f;
  float gbrx = gx + gw * 0.5f, gbry = gy + gh * 0.5f;
  float ptlx = p.x - p.z * 0.5f, ptly = p.y - p.w * 0.5f;
  float pbrx = p.x + p.z * 0.5f, pbry = p.y + p.w * 0.5f;
  float tlx = fmaxf(gtlx, ptlx), tly = fmaxf(gtly, ptly);
  float brx = fminf(gbrx, pbrx), bry = fminf(gbry, pbry);
  float inter = ((tlx < brx) && (tly < bry)) ? (brx - tlx) * (bry - tly) : 0.0f;
  float ag = gw * gh, ap = p.z * p.w;
  return inter * frcp(ag + ap - inter + 1e-16f);
}

// cost from staged class logit x — identical instruction chain everywhere.
__device__ __forceinline__ float cost_from_x(float x, float lso, float slr,
                                             unsigned int am, int g,
                                             float gx, float gy, float gw, float gh,
                                             float4 pb, float& iou_out) {
  float u = __logf(1.0f + __expf(-fabsf(x)));
  float lsx = fminf(x, 0.0f) - u;
  float lpr = 0.5f * (lsx + lso);
  float p   = __expf(lpr);
  float l1p = fmaxf(__logf(1.0f - p), -100.0f);
  float wv  = fmaxf(lpr, -100.0f) - l1p;          // lp - l1p
  float iou = iou_raw(gx, gy, gw, gh, pb);
  iou_out = iou;
  float cst = -(wv + slr) - 3.0f * __logf(iou + 1e-8f);
  if (!((am >> g) & 1u)) cst += 100000.0f;
  return cst;
}

__device__ __forceinline__ float giou_loss(float4 bb, float gx, float gy, float gw, float gh) {
  float btlx = bb.x - bb.z * 0.5f, btly = bb.y - bb.w * 0.5f;
  float bbrx = bb.x + bb.z * 0.5f, bbry = bb.y + bb.w * 0.5f;
  float gtlx = gx - gw * 0.5f, gtly = gy - gh * 0.5f;
  float gbrx = gx + gw * 0.5f, gbry = gy + gh * 0.5f;
  float tlx = fmaxf(btlx, gtlx), tly = fmaxf(btly, gtly);
  float brx = fminf(bbrx, gbrx), bry = fminf(bbry, gbry);
  float area_b = bb.z * bb.w, area_g = gw * gh;
  float inter = ((tlx < brx) && (tly < bry)) ? (brx - tlx) * (bry - tly) : 0.0f;
  float uni = area_b + area_g - inter;
  float iou = inter / (uni + 1e-16f);
  float ctlx = fminf(btlx, gtlx), ctly = fminf(btly, gtly);
  float cbrx = fmaxf(bbrx, gbrx), cbry = fmaxf(bbry, gbry);
  float area_c = fmaxf((cbrx - ctlx) * (cbry - ctly), 1e-16f);
  float giou = iou - (area_c - uni) / area_c;
  giou = fminf(fmaxf(giou, -1.0f), 1.0f);
  return 1.0f - giou;
}

// ---------- kA: geometry + compaction + decode + obj-BCE + DENSE class sweep ----------
// All 64 lanes stream all 80 class planes coalesced (full line utilization, BW-bound);
// fg lanes additionally write sb/meta and stage the 20 gt-class logits via a
// per-class g-bitmask. Accumulation order c=0..79 is identical to prior rounds.
__global__ __launch_bounds__(256) void kA(const float* __restrict__ p8,
                                          const float* __restrict__ p16,
                                          const float* __restrict__ p32,
                                          const float* __restrict__ labels,
                                          int* __restrict__ n_fg_cnt,
                                          float4* __restrict__ meta_c,
                                          float4* __restrict__ bbox_c,
                                          float* __restrict__ sb_c,
                                          float* __restrict__ x_tbl,
                                          unsigned int* __restrict__ match_c,
                                          float* __restrict__ blk_obj) {
  __shared__ float s_gt[NG * 4];
  __shared__ unsigned int s_c2g[NCL];    // per-class bitmask of g's with that class
  __shared__ unsigned int s_wcnt[4];
  __shared__ float s_part[4];
  __shared__ unsigned int s_base;

  int blk = blockIdx.x, b = blockIdx.y, tid = threadIdx.x, lane = tid & 63, wid = tid >> 6;
  size_t bo = (size_t)b * NAP;

  if (tid < NCL) s_c2g[tid] = 0u;
  __syncthreads();
  if (tid < NG) {
    s_gt[tid * 4 + 0] = labels[((size_t)b * NG + tid) * 5 + 0];
    s_gt[tid * 4 + 1] = labels[((size_t)b * NG + tid) * 5 + 1];
    s_gt[tid * 4 + 2] = labels[((size_t)b * NG + tid) * 5 + 2];
    s_gt[tid * 4 + 3] = labels[((size_t)b * NG + tid) * 5 + 3];
    int c = (int)labels[((size_t)b * NG + tid) * 5 + 4];
    atomicOr(&s_c2g[c], 1u << tid);
  }
  __syncthreads();

  // ---- phase 1: fg test ----
  int a = blk * 256 + tid;
  match_c[bo + a] = 0u;                  // NBLK*256 == NAP: full coverage
  bool fg = false;
  unsigned int msk = 0u;
  float bce_obj = 0.0f, obj = 0.0f;
  const float* base = nullptr; int hw = 0, HW = 0, xg = 0, yg = 0; float fs = 8.f;
  if (a < NA) {
    anchor_info(a, p8, p16, p32, b, base, hw, HW, xg, yg, fs);
    obj = base[4 * HW + hw];             // coalesced obj-plane stream
    bce_obj = bce0(obj);
    float xc = ((float)xg + 0.5f) * fs;
    float yc = ((float)yg + 0.5f) * fs;
    float r = 2.5f * fs;
#pragma unroll
    for (int g = 0; g < NG; ++g) {
      float gx = s_gt[g * 4 + 0], gy = s_gt[g * 4 + 1];
      float gw = s_gt[g * 4 + 2], gh = s_gt[g * 4 + 3];
      bool inb = (xc > gx - 0.5f * gw) && (xc < gx + 0.5f * gw) &&
                 (yc > gy - 0.5f * gh) && (yc < gy + 0.5f * gh);
      bool inc = (xc > gx - r) && (xc < gx + r) && (yc > gy - r) && (yc < gy + r);
      fg = fg || inb || inc;
      if (inb && inc) msk |= (1u << g);
    }
  }

  unsigned long long bm = __ballot(fg);
#pragma unroll
  for (int off = 32; off; off >>= 1) bce_obj += __shfl_down(bce_obj, off, 64);
  if (lane == 0) { s_wcnt[wid] = (unsigned int)__popcll(bm); s_part[wid] = bce_obj; }
  __syncthreads();
  if (tid == 0) {
    unsigned int cnt = s_wcnt[0] + s_wcnt[1] + s_wcnt[2] + s_wcnt[3];
    s_base = cnt ? (unsigned int)atomicAdd(&n_fg_cnt[b], (int)cnt) : 0u;
    blk_obj[b * NBLK + blk] = s_part[0] + s_part[1] + s_part[2] + s_part[3];
  }
  __syncthreads();

  int ci = -1;
  if (fg) {
    unsigned int li = 0;
    for (int w = 0; w < wid; ++w) li += s_wcnt[w];
    li += (unsigned int)__popcll(bm & ((1ull << lane) - 1ull));
    ci = (int)(s_base + li);
  }

  float lso = 0.0f;
  if (a < NA) {
    float uo = __logf(1.0f + __expf(-fabsf(obj)));
    lso = fminf(obj, 0.0f) - uo;         // log(sigmoid(obj))
  }

  // ---- dense class sweep c = 0..79 (ALL lanes active -> coalesced, BW-bound) ----
  float sb = 0.0f, sl = 0.0f;
  if (a < NA) {
    const float* cb = base + (size_t)5 * HW + hw;
#pragma unroll 8
    for (int c = 0; c < NCL; ++c) {
      float x = cb[(size_t)c * HW];      // full-line coalesced across lanes
      float u = __logf(1.0f + __expf(-fabsf(x)));
      sb += fmaxf(x, 0.0f) + u;          // bce(x,0)
      float lsx = fminf(x, 0.0f) - u;    // log(sigmoid(x))
      float lpr = 0.5f * (lsx + lso);    // log p
      float p   = __expf(lpr);
      sl += fmaxf(__logf(1.0f - p), -100.0f);
      unsigned int m = s_c2g[c];
      if (fg && m) {
        do {
          int g = __ffs(m) - 1; m &= m - 1u;
          x_tbl[((size_t)b * NG + g) * NAP + ci] = x;   // staged gt-class logit
        } while (m);
      }
    }
  }

  if (!fg) return;

  // decode bbox (fg lanes only)
  float v0 = base[hw];
  float v1 = base[HW + hw];
  float v2 = base[2 * HW + hw];
  float v3 = base[3 * HW + hw];
  float4 bb4 = make_float4((v0 + (float)xg) * fs, (v1 + (float)yg) * fs,
                           __expf(v2) * fs, __expf(v3) * fs);
  bbox_c[bo + ci] = bb4;
  sb_c[bo + ci] = sb;
  meta_c[bo + ci] = make_float4(lso, sl, __uint_as_float(msk), obj);
}

// ---------- kBG: per-(b,g) packed-stream cost/iou + single-pass top-k + mark,
//             then per-image ticket finalize + final-scalar ticket ----------
__global__ __launch_bounds__(256) void kBG(const float* __restrict__ labels,
                                           const int* __restrict__ n_fg,
                                           const float4* __restrict__ meta_c,
                                           const float4* __restrict__ bbox_c,
                                           const float* __restrict__ sb_c,
                                           const float* __restrict__ x_tbl,
                                           unsigned int* __restrict__ match_c,
                                           const float* __restrict__ blk_obj,
                                           float* __restrict__ accum,
                                           int* __restrict__ done_g,
                                           int* __restrict__ done_img,
                                           float* __restrict__ out) {
  __shared__ float s_gt[NG * 5];
  __shared__ float s_wt[4 * 10];
  __shared__ float s_wc[4 * 10];
  __shared__ int   s_wi[4 * 10];
  __shared__ float s_red[16];
  __shared__ int   s_flag;

  int g = blockIdx.x, b = blockIdx.y, tid = threadIdx.x;
  int lane = tid & 63, wid = tid >> 6;
  int n = n_fg[b];
  size_t bo = (size_t)b * NAP;
  const float* __restrict__ xrow = x_tbl + ((size_t)b * NG + g) * NAP;

  if (tid < NG * 5) s_gt[tid] = labels[(size_t)b * NG * 5 + tid];
  __syncthreads();

  float ggx = s_gt[g * 5], ggy = s_gt[g * 5 + 1];
  float ggw = s_gt[g * 5 + 2], ggh = s_gt[g * 5 + 3];

  float t10[10];          // top-10 ious (descending)
  float c10v[10];         // top-10 smallest costs (ascending)
  int   c10i[10];
#pragma unroll
  for (int j = 0; j < 10; ++j) { t10[j] = 0.0f; c10v[j] = 3.4e38f; c10i[j] = 0x7fffffff; }

  for (int ci = tid; ci < n; ci += 256) {
    float4 me = meta_c[bo + ci];
    float4 pb = bbox_c[bo + ci];
    float x = xrow[ci];
    unsigned int am = __float_as_uint(me.z);
    float iou;
    float cst = cost_from_x(x, me.x, me.y, am, g, ggx, ggy, ggw, ggh, pb, iou);
    if (iou > t10[9]) {
      t10[9] = iou;
#pragma unroll
      for (int q = 9; q > 0; --q) {
        if (t10[q] > t10[q - 1]) { float t = t10[q]; t10[q] = t10[q - 1]; t10[q - 1] = t; }
        else break;
      }
    }
    if (cst < c10v[9] || (cst == c10v[9] && ci < c10i[9])) {
      c10v[9] = cst; c10i[9] = ci;
#pragma unroll
      for (int q = 9; q > 0; --q) {
        if (c10v[q] < c10v[q - 1] ||
            (c10v[q] == c10v[q - 1] && c10i[q] < c10i[q - 1])) {
          float tv = c10v[q]; c10v[q] = c10v[q - 1]; c10v[q - 1] = tv;
          int   ti = c10i[q]; c10i[q] = c10i[q - 1]; c10i[q - 1] = ti;
        } else break;
      }
    }
  }

  // per-wave extraction: 10 rounds; iou-max and cost-min chains interleaved (ILP)
  for (int r = 0; r < 10; ++r) {
    float v = t10[0];
    float bv = v;
    float cv = c10v[0]; int cix = c10i[0];
    float cbv = cv;     int cbi = cix;
#pragma unroll
    for (int off = 32; off; off >>= 1) {
      bv = fmaxf(bv, __shfl_down(bv, off, 64));
      float ov = __shfl_down(cbv, off, 64);
      int   oi = __shfl_down(cbi, off, 64);
      if (ov < cbv || (ov == cbv && oi < cbi)) { cbv = ov; cbi = oi; }
    }
    bv  = __shfl(bv, 0, 64);
    cbv = __shfl(cbv, 0, 64);
    cbi = __shfl(cbi, 0, 64);
    unsigned long long won = __ballot(v == bv);
    if (lane == __ffsll(won) - 1) {
#pragma unroll
      for (int q = 0; q < 9; ++q) t10[q] = t10[q + 1];
      t10[9] = -1.0f;
    }
    if (cv == cbv && cix == cbi) {       // unique owner (ci unique within block)
#pragma unroll
      for (int q = 0; q < 9; ++q) { c10v[q] = c10v[q + 1]; c10i[q] = c10i[q + 1]; }
      c10v[9] = 3.4e38f; c10i[9] = 0x7fffffff;
    }
    if (lane == 0) {
      s_wt[wid * 10 + r] = bv;
      s_wc[wid * 10 + r] = cbv;
      s_wi[wid * 10 + r] = cbi;
    }
  }
  __syncthreads();

  if (tid == 0) {
    // merge 4 sorted desc iou lists -> dyn_k (sum in desc order, trunc, clip 1)
    int p0 = 0, p1 = 0, p2 = 0, p3 = 0;
    float s = 0.0f;
    for (int r = 0; r < 10; ++r) {
      float v0 = (p0 < 10) ? s_wt[p0]      : -2.0f;
      float v1 = (p1 < 10) ? s_wt[10 + p1] : -2.0f;
      float v2 = (p2 < 10) ? s_wt[20 + p2] : -2.0f;
      float v3 = (p3 < 10) ? s_wt[30 + p3] : -2.0f;
      float m = fmaxf(fmaxf(v0, v1), fmaxf(v2, v3));
      s += m;
      if (m == v0) ++p0; else if (m == v1) ++p1; else if (m == v2) ++p2; else ++p3;
    }
    int k = (int)s;
    if (k < 1) k = 1;
    // merge 4 sorted asc (cost,ci) lists -> mark k smallest
    int q[4] = {0, 0, 0, 0};
    for (int it = 0; it < k; ++it) {
      float bv = 3.3e38f; int bi = 0x7fffffff; int sel = -1;
#pragma unroll
      for (int w = 0; w < 4; ++w) {
        if (q[w] < 10) {
          float v = s_wc[w * 10 + q[w]];
          int   i = s_wi[w * 10 + q[w]];
          if (v < bv || (v == bv && i < bi)) { bv = v; bi = i; sel = w; }
        }
      }
      if (sel < 0 || bv >= 1e37f) break;   // exhausted real candidates
      atomicOr(&match_c[bo + bi], 1u << g);
      ++q[sel];
    }
    // per-image ticket
    __threadfence();
    s_flag = (atomicAdd(&done_g[b], 1) == NG - 1) ? 1 : 0;
  }
  __syncthreads();
  if (!s_flag) return;

  // ---- finalize (winner block of image b) — packed tables only, no gathers ----
  float li = 0.0f, oe = 0.0f, lc = 0.0f, nf = 0.0f;
  for (int ci = tid; ci < n; ci += 256) {
    unsigned int m = atomicOr(&match_c[bo + ci], 0u);   // coherence-point read
    if (m == 0u) continue;
    float4 me = meta_c[bo + ci];
    float4 pb = bbox_c[bo + ci];
    unsigned int am = __float_as_uint(me.z);
    int mg;
    if (m & (m - 1)) {
      float bestc = 3.4e38f; mg = 0;
      for (int gq = 0; gq < NG; ++gq) {
        float xq = x_tbl[((size_t)b * NG + gq) * NAP + ci];
        float iouq;
        float cq = cost_from_x(xq, me.x, me.y, am, gq, s_gt[gq * 5], s_gt[gq * 5 + 1],
                               s_gt[gq * 5 + 2], s_gt[gq * 5 + 3], pb, iouq);
        if (cq < bestc) { bestc = cq; mg = gq; }
      }
    } else {
      mg = __ffs(m) - 1;
    }
    float gx = s_gt[mg * 5], gy = s_gt[mg * 5 + 1];
    float gw = s_gt[mg * 5 + 2], gh = s_gt[mg * 5 + 3];
    float piou = iou_raw(gx, gy, gw, gh, pb);
    li += giou_loss(pb, gx, gy, gw, gh);
    float xcls = x_tbl[((size_t)b * NG + mg) * NAP + ci];
    lc += sb_c[bo + ci] - xcls * piou;   // bce(x,t) = bce(x,0) - x*t
    oe += me.w;                          // obj logit: bce(x,1) = bce(x,0) - x
    nf += 1.0f;
  }

  float vals[4] = {li, oe, lc, nf};
#pragma unroll
  for (int q2 = 0; q2 < 4; ++q2) {
#pragma unroll
    for (int off = 32; off; off >>= 1) vals[q2] += __shfl_down(vals[q2], off, 64);
  }
  if (lane == 0) {
    s_red[wid * 4 + 0] = vals[0];
    s_red[wid * 4 + 1] = vals[1];
    s_red[wid * 4 + 2] = vals[2];
    s_red[wid * 4 + 3] = vals[3];
  }
  __syncthreads();
  if (tid < 4) {
    const int slot[4] = {0, 2, 3, 4};
    float s = s_red[tid] + s_red[4 + tid] + s_red[8 + tid] + s_red[12 + tid];
    atomicAdd(&accum[slot[tid]], s);
  }

  // ---- final ticket: last image's finalize block emits the scalar ----
  if (tid == 0) {
    __threadfence();
    s_flag = (atomicAdd(done_img, 1) == NB - 1) ? 1 : 0;
  }
  __syncthreads();
  if (!s_flag) return;

  float s = 0.0f;
  for (int i = tid; i < NB * NBLK; i += 256) s += blk_obj[i];  // obj-BCE base
#pragma unroll
  for (int off = 32; off; off >>= 1) s += __shfl_down(s, off, 64);
  if ((tid & 63) == 0) s_red[tid >> 6] = s;
  __syncthreads();
  if (tid == 0) {
    float obj_base = s_red[0] + s_red[1] + s_red[2] + s_red[3];
    float loss_iou = atomicAdd(&accum[0], 0.0f);   // coherent read-backs
    float oex      = atomicAdd(&accum[2], 0.0f);
    float loss_cls = atomicAdd(&accum[3], 0.0f);
    float num_fg   = atomicAdd(&accum[4], 0.0f);
    float loss_obj = obj_base - oex;
    out[0] = (5.0f * loss_iou + loss_obj + loss_cls) / fmaxf(num_fg, 1.0f);
  }
}

// ---------- launch ----------
extern "C" void kernel_launch(void* const* d_in, const int* in_sizes, int n_in,
                              void* d_out, int out_size, void* d_ws, size_t ws_size,
                              hipStream_t stream) {
  const float* p8     = (const float*)d_in[0];
  const float* p16    = (const float*)d_in[1];
  const float* p32    = (const float*)d_in[2];
  const float* labels = (const float*)d_in[3];
  float* out = (float*)d_out;

  const size_t BAP = (size_t)NB * NAP;     // 270336
  char* w = (char*)d_ws;
  float4*       bbox_c   = (float4*)w;                             // 4.33 MB, 16B-aligned
  float4*       meta_c   = (float4*)(w + BAP * 16);                // 4.33 MB
  float*        x_tbl    = (float*)(w + BAP * 32);                 // NB*NG*NAP*4 = 21.6 MB
  char*         w2       = (char*)x_tbl + (size_t)NB * NG * NAP * 4;
  float*        sb_c     = (float*)(w2);
  unsigned int* match_c  = (unsigned int*)(w2 + BAP * 4);
  char*         w3       = w2 + BAP * 8;
  // zeroed region (512 B): n_fg(32i)@0, accum(8f)@128, done_g(32i)@256, done_img@384
  int*          n_fg     = (int*)w3;
  float*        accum    = (float*)(w3 + 128);
  int*          done_g   = (int*)(w3 + 256);
  int*          done_img = (int*)(w3 + 384);
  float*        blk_obj  = (float*)(w3 + 512);                     // NB*NBLK floats (4224 B)

  hipMemsetAsync(w3, 0, 512, stream);

  kA <<<dim3(NBLK, NB), dim3(256), 0, stream>>>(p8, p16, p32, labels, n_fg, meta_c,
                                                bbox_c, sb_c, x_tbl, match_c, blk_obj);
  kBG<<<dim3(NG, NB), dim3(256), 0, stream>>>(labels, n_fg, meta_c, bbox_c, sb_c, x_tbl,
                                              match_c, blk_obj, accum, done_g,
                                              done_img, out);
}

// Round 9
// 194.553 us; speedup vs baseline: 1.0712x; 1.0278x over previous
//
#include <hip/hip_runtime.h>
#include <cstdint>
#include <cstddef>

#define NA 8400   // anchors per image: 80*80 + 40*40 + 20*20
#define NAP 8448  // padded stride (33*256)
#define NB 32     // batch
#define NG 20     // ground truths per image
#define NCL 80    // classes
#define NBLK 33   // 256-thread blocks per image

// ---------- fast math ----------
__device__ __forceinline__ float frcp(float x) { return __builtin_amdgcn_rcpf(x); }
__device__ __forceinline__ float bce0(float x) {
  return fmaxf(x, 0.0f) + __logf(1.0f + __expf(-fabsf(x)));
}

__device__ __forceinline__ void anchor_info(int a, const float* p8, const float* p16,
                                            const float* p32, int b, const float*& base,
                                            int& hw, int& HW, int& xg, int& yg, float& fs) {
  if (a < 6400)      { hw = a;        HW = 6400; xg = hw % 80; yg = hw / 80; fs = 8.f;
                       base = p8  + (size_t)b * 85 * 6400; }
  else if (a < 8000) { hw = a - 6400; HW = 1600; xg = hw % 40; yg = hw / 40; fs = 16.f;
                       base = p16 + (size_t)b * 85 * 1600; }
  else               { hw = a - 8000; HW = 400;  xg = hw % 20; yg = hw / 20; fs = 32.f;
                       base = p32 + (size_t)b * 85 * 400; }
}

__device__ __forceinline__ float iou_raw(float gx, float gy, float gw, float gh, float4 p) {
  float gtlx = gx - gw * 0.5f, gtly = gy - gh * 0.5f;
  float gbrx = gx + gw * 0.5f, gbry = gy + gh * 0.5f;
  float ptlx = p.x - p.z * 0.5f, ptly = p.y - p.w * 0.5f;
  float pbrx = p.x + p.z * 0.5f, pbry = p.y + p.w * 0.5f;
  float tlx = fmaxf(gtlx, ptlx), tly = fmaxf(gtly, ptly);
  float brx = fminf(gbrx, pbrx), bry = fminf(gbry, pbry);
  float inter = ((tlx < brx) && (tly < bry)) ? (brx - tlx) * (bry - tly) : 0.0f;
  float ag = gw * gh, ap = p.z * p.w;
  return inter * frcp(ag + ap - inter + 1e-16f);
}

// cost from staged class logit x — identical instruction chain everywhere.
__device__ __forceinline__ float cost_from_x(float x, float lso, float slr,
                                             unsigned int am, int g,
                                             float gx, float gy, float gw, float gh,
                                             float4 pb, float& iou_out) {
  float u = __logf(1.0f + __expf(-fabsf(x)));
  float lsx = fminf(x, 0.0f) - u;
  float lpr = 0.5f * (lsx + lso);
  float p   = __expf(lpr);
  float l1p = fmaxf(__logf(1.0f - p), -100.0f);
  float wv  = fmaxf(lpr, -100.0f) - l1p;          // lp - l1p
  float iou = iou_raw(gx, gy, gw, gh, pb);
  iou_out = iou;
  float cst = -(wv + slr) - 3.0f * __logf(iou + 1e-8f);
  if (!((am >> g) & 1u)) cst += 100000.0f;
  return cst;
}

__device__ __forceinline__ float giou_loss(float4 bb, float gx, float gy, float gw, float gh) {
  float btlx = bb.x - bb.z * 0.5f, btly = bb.y - bb.w * 0.5f;
  float bbrx = bb.x + bb.z * 0.5f, bbry = bb.y + bb.w * 0.5f;
  float gtlx = gx - gw * 0.5f, gtly = gy - gh * 0.5f;
  float gbrx = gx + gw * 0.5f, gbry = gy + gh * 0.5f;
  float tlx = fmaxf(btlx, gtlx), tly = fmaxf(btly, gtly);
  float brx = fminf(bbrx, gbrx), bry = fminf(bbry, gbry);
  float area_b = bb.z * bb.w, area_g = gw * gh;
  float inter = ((tlx < brx) && (tly < bry)) ? (brx - tlx) * (bry - tly) : 0.0f;
  float uni = area_b + area_g - inter;
  float iou = inter / (uni + 1e-16f);
  float ctlx = fminf(btlx, gtlx), ctly = fminf(btly, gtly);
  float cbrx = fmaxf(bbrx, gbrx), cbry = fmaxf(bbry, gbry);
  float area_c = fmaxf((cbrx - ctlx) * (cbry - ctly), 1e-16f);
  float giou = iou - (area_c - uni) / area_c;
  giou = fminf(fmaxf(giou, -1.0f), 1.0f);
  return 1.0f - giou;
}

// ---------- kA: geometry + compaction + decode + obj-BCE + VECTORIZED class sweep ----
// Phase 2: each lane loads float4 (4 anchors) per class; the 4 waves partition the 80
// classes (wave w -> [20w, 20w+20)). 4x bytes in flight per load vs scalar sweep.
// Per-anchor sums reduced across waves in LDS (4-group order, as R1/R2's 8x10 scheme).
__global__ __launch_bounds__(256) void kA(const float* __restrict__ p8,
                                          const float* __restrict__ p16,
                                          const float* __restrict__ p32,
                                          const float* __restrict__ labels,
                                          int* __restrict__ n_fg_cnt,
                                          float4* __restrict__ meta_c,
                                          float4* __restrict__ bbox_c,
                                          float* __restrict__ sb_c,
                                          float* __restrict__ x_tbl,
                                          unsigned int* __restrict__ match_c,
                                          float* __restrict__ blk_obj) {
  __shared__ float s_gt[NG * 4];
  __shared__ unsigned int s_c2g[NCL];    // per-class bitmask of g's with that class
  __shared__ float s_lso[256];
  __shared__ int   s_ci[256];
  __shared__ float s_sb[4][256];         // per-wave partial bce(x,0) sums
  __shared__ float s_sl[4][256];         // per-wave partial log1p(-p) sums
  __shared__ unsigned int s_wcnt[4];
  __shared__ float s_part[4];
  __shared__ unsigned int s_base;

  int blk = blockIdx.x, b = blockIdx.y, tid = threadIdx.x, lane = tid & 63, wid = tid >> 6;
  size_t bo = (size_t)b * NAP;

  if (tid < NCL) s_c2g[tid] = 0u;
  __syncthreads();
  if (tid < NG) {
    s_gt[tid * 4 + 0] = labels[((size_t)b * NG + tid) * 5 + 0];
    s_gt[tid * 4 + 1] = labels[((size_t)b * NG + tid) * 5 + 1];
    s_gt[tid * 4 + 2] = labels[((size_t)b * NG + tid) * 5 + 2];
    s_gt[tid * 4 + 3] = labels[((size_t)b * NG + tid) * 5 + 3];
    int c = (int)labels[((size_t)b * NG + tid) * 5 + 4];
    atomicOr(&s_c2g[c], 1u << tid);
  }
  __syncthreads();

  // ---- phase 1: fg test + compaction + bbox decode ----
  int a = blk * 256 + tid;
  match_c[bo + a] = 0u;                  // NBLK*256 == NAP: full coverage
  bool fg = false;
  unsigned int msk = 0u;
  float bce_obj = 0.0f, obj = 0.0f;
  const float* base = nullptr; int hw = 0, HW = 0, xg = 0, yg = 0; float fs = 8.f;
  if (a < NA) {
    anchor_info(a, p8, p16, p32, b, base, hw, HW, xg, yg, fs);
    obj = base[4 * HW + hw];             // coalesced obj-plane stream
    bce_obj = bce0(obj);
    float xc = ((float)xg + 0.5f) * fs;
    float yc = ((float)yg + 0.5f) * fs;
    float r = 2.5f * fs;
#pragma unroll
    for (int g = 0; g < NG; ++g) {
      float gx = s_gt[g * 4 + 0], gy = s_gt[g * 4 + 1];
      float gw = s_gt[g * 4 + 2], gh = s_gt[g * 4 + 3];
      bool inb = (xc > gx - 0.5f * gw) && (xc < gx + 0.5f * gw) &&
                 (yc > gy - 0.5f * gh) && (yc < gy + 0.5f * gh);
      bool inc = (xc > gx - r) && (xc < gx + r) && (yc > gy - r) && (yc < gy + r);
      fg = fg || inb || inc;
      if (inb && inc) msk |= (1u << g);
    }
  }

  unsigned long long bm = __ballot(fg);
#pragma unroll
  for (int off = 32; off; off >>= 1) bce_obj += __shfl_down(bce_obj, off, 64);
  if (lane == 0) { s_wcnt[wid] = (unsigned int)__popcll(bm); s_part[wid] = bce_obj; }
  __syncthreads();
  if (tid == 0) {
    unsigned int cnt = s_wcnt[0] + s_wcnt[1] + s_wcnt[2] + s_wcnt[3];
    s_base = cnt ? (unsigned int)atomicAdd(&n_fg_cnt[b], (int)cnt) : 0u;
    blk_obj[b * NBLK + blk] = s_part[0] + s_part[1] + s_part[2] + s_part[3];
  }
  __syncthreads();

  float lso = 0.0f;
  if (a < NA) {
    float uo = __logf(1.0f + __expf(-fabsf(obj)));
    lso = fminf(obj, 0.0f) - uo;         // log(sigmoid(obj))
  }
  s_lso[tid] = lso;

  int ci = -1;
  if (fg) {
    unsigned int li = 0;
    for (int w = 0; w < wid; ++w) li += s_wcnt[w];
    li += (unsigned int)__popcll(bm & ((1ull << lane) - 1ull));
    ci = (int)(s_base + li);
    // decode bbox now (scattered 4-plane loads, fg lanes only)
    float v0 = base[hw];
    float v1 = base[HW + hw];
    float v2 = base[2 * HW + hw];
    float v3 = base[3 * HW + hw];
    bbox_c[bo + ci] = make_float4((v0 + (float)xg) * fs, (v1 + (float)yg) * fs,
                                  __expf(v2) * fs, __expf(v3) * fs);
  }
  s_ci[tid] = ci;
  __syncthreads();

  // ---- phase 2: vectorized class sweep — lane owns 4 anchors, wave owns 20 classes ----
  int a0 = blk * 256 + (lane << 2);
  bool valid = a0 < NA;
  const float* vbase = nullptr; int vhw = 0, vHW = 0, dxg, dyg; float dfs;
  if (valid) anchor_info(a0, p8, p16, p32, b, vbase, vhw, vHW, dxg, dyg, dfs);
  float l4[4], sb4[4] = {0.f, 0.f, 0.f, 0.f}, sl4[4] = {0.f, 0.f, 0.f, 0.f};
  int   ci4[4];
#pragma unroll
  for (int j = 0; j < 4; ++j) {
    l4[j]  = s_lso[(lane << 2) + j];
    ci4[j] = s_ci[(lane << 2) + j];
  }

  if (valid) {
    const float* cb = vbase + (size_t)5 * vHW + vhw;
#pragma unroll 4
    for (int cc = 0; cc < 20; ++cc) {
      int c = wid * 20 + cc;
      float4 x4 = *reinterpret_cast<const float4*>(cb + (size_t)c * vHW);
      float xa[4] = {x4.x, x4.y, x4.z, x4.w};
#pragma unroll
      for (int j = 0; j < 4; ++j) {
        float x = xa[j];
        float u = __logf(1.0f + __expf(-fabsf(x)));
        sb4[j] += fmaxf(x, 0.0f) + u;          // bce(x,0)
        float lsx = fminf(x, 0.0f) - u;        // log(sigmoid(x))
        float lpr = 0.5f * (lsx + l4[j]);      // log p
        float p   = __expf(lpr);
        sl4[j] += fmaxf(__logf(1.0f - p), -100.0f);
      }
      unsigned int m = s_c2g[c];
      while (m) {
        int g = __ffs(m) - 1; m &= m - 1u;
        size_t rowo = ((size_t)b * NG + g) * NAP;
#pragma unroll
        for (int j = 0; j < 4; ++j)
          if (ci4[j] >= 0) x_tbl[rowo + ci4[j]] = xa[j];
      }
    }
  }
#pragma unroll
  for (int j = 0; j < 4; ++j) {
    s_sb[wid][(lane << 2) + j] = sb4[j];
    s_sl[wid][(lane << 2) + j] = sl4[j];
  }
  __syncthreads();

  // ---- phase 3: reduce partials (w = 0..3 in order) and emit outputs ----
  if (ci >= 0) {
    float sb = ((s_sb[0][tid] + s_sb[1][tid]) + s_sb[2][tid]) + s_sb[3][tid];
    float sl = ((s_sl[0][tid] + s_sl[1][tid]) + s_sl[2][tid]) + s_sl[3][tid];
    sb_c[bo + ci] = sb;
    meta_c[bo + ci] = make_float4(lso, sl, __uint_as_float(msk), obj);
  }
}

// ---------- kBG: per-(b,g) packed-stream cost/iou + single-pass top-k + mark,
//             then per-image ticket finalize + final-scalar ticket ----------
__global__ __launch_bounds__(256) void kBG(const float* __restrict__ labels,
                                           const int* __restrict__ n_fg,
                                           const float4* __restrict__ meta_c,
                                           const float4* __restrict__ bbox_c,
                                           const float* __restrict__ sb_c,
                                           const float* __restrict__ x_tbl,
                                           unsigned int* __restrict__ match_c,
                                           const float* __restrict__ blk_obj,
                                           float* __restrict__ accum,
                                           int* __restrict__ done_g,
                                           int* __restrict__ done_img,
                                           float* __restrict__ out) {
  __shared__ float s_gt[NG * 5];
  __shared__ float s_wt[4 * 10];
  __shared__ float s_wc[4 * 10];
  __shared__ int   s_wi[4 * 10];
  __shared__ float s_red[16];
  __shared__ int   s_flag;

  int g = blockIdx.x, b = blockIdx.y, tid = threadIdx.x;
  int lane = tid & 63, wid = tid >> 6;
  int n = n_fg[b];
  size_t bo = (size_t)b * NAP;
  const float* __restrict__ xrow = x_tbl + ((size_t)b * NG + g) * NAP;

  if (tid < NG * 5) s_gt[tid] = labels[(size_t)b * NG * 5 + tid];
  __syncthreads();

  float ggx = s_gt[g * 5], ggy = s_gt[g * 5 + 1];
  float ggw = s_gt[g * 5 + 2], ggh = s_gt[g * 5 + 3];

  float t10[10];          // top-10 ious (descending)
  float c10v[10];         // top-10 smallest costs (ascending)
  int   c10i[10];
#pragma unroll
  for (int j = 0; j < 10; ++j) { t10[j] = 0.0f; c10v[j] = 3.4e38f; c10i[j] = 0x7fffffff; }

  for (int ci = tid; ci < n; ci += 256) {
    float4 me = meta_c[bo + ci];
    float4 pb = bbox_c[bo + ci];
    float x = xrow[ci];
    unsigned int am = __float_as_uint(me.z);
    float iou;
    float cst = cost_from_x(x, me.x, me.y, am, g, ggx, ggy, ggw, ggh, pb, iou);
    if (iou > t10[9]) {
      t10[9] = iou;
#pragma unroll
      for (int q = 9; q > 0; --q) {
        if (t10[q] > t10[q - 1]) { float t = t10[q]; t10[q] = t10[q - 1]; t10[q - 1] = t; }
        else break;
      }
    }
    if (cst < c10v[9] || (cst == c10v[9] && ci < c10i[9])) {
      c10v[9] = cst; c10i[9] = ci;
#pragma unroll
      for (int q = 9; q > 0; --q) {
        if (c10v[q] < c10v[q - 1] ||
            (c10v[q] == c10v[q - 1] && c10i[q] < c10i[q - 1])) {
          float tv = c10v[q]; c10v[q] = c10v[q - 1]; c10v[q - 1] = tv;
          int   ti = c10i[q]; c10i[q] = c10i[q - 1]; c10i[q - 1] = ti;
        } else break;
      }
    }
  }

  // per-wave extraction: 10 rounds; iou-max and cost-min chains interleaved (ILP)
  for (int r = 0; r < 10; ++r) {
    float v = t10[0];
    float bv = v;
    float cv = c10v[0]; int cix = c10i[0];
    float cbv = cv;     int cbi = cix;
#pragma unroll
    for (int off = 32; off; off >>= 1) {
      bv = fmaxf(bv, __shfl_down(bv, off, 64));
      float ov = __shfl_down(cbv, off, 64);
      int   oi = __shfl_down(cbi, off, 64);
      if (ov < cbv || (ov == cbv && oi < cbi)) { cbv = ov; cbi = oi; }
    }
    bv  = __shfl(bv, 0, 64);
    cbv = __shfl(cbv, 0, 64);
    cbi = __shfl(cbi, 0, 64);
    unsigned long long won = __ballot(v == bv);
    if (lane == __ffsll(won) - 1) {
#pragma unroll
      for (int q = 0; q < 9; ++q) t10[q] = t10[q + 1];
      t10[9] = -1.0f;
    }
    if (cv == cbv && cix == cbi) {       // unique owner (ci unique within block)
#pragma unroll
      for (int q = 0; q < 9; ++q) { c10v[q] = c10v[q + 1]; c10i[q] = c10i[q + 1]; }
      c10v[9] = 3.4e38f; c10i[9] = 0x7fffffff;
    }
    if (lane == 0) {
      s_wt[wid * 10 + r] = bv;
      s_wc[wid * 10 + r] = cbv;
      s_wi[wid * 10 + r] = cbi;
    }
  }
  __syncthreads();

  if (tid == 0) {
    // merge 4 sorted desc iou lists -> dyn_k (sum in desc order, trunc, clip 1)
    int p0 = 0, p1 = 0, p2 = 0, p3 = 0;
    float s = 0.0f;
    for (int r = 0; r < 10; ++r) {
      float v0 = (p0 < 10) ? s_wt[p0]      : -2.0f;
      float v1 = (p1 < 10) ? s_wt[10 + p1] : -2.0f;
      float v2 = (p2 < 10) ? s_wt[20 + p2] : -2.0f;
      float v3 = (p3 < 10) ? s_wt[30 + p3] : -2.0f;
      float m = fmaxf(fmaxf(v0, v1), fmaxf(v2, v3));
      s += m;
      if (m == v0) ++p0; else if (m == v1) ++p1; else if (m == v2) ++p2; else ++p3;
    }
    int k = (int)s;
    if (k < 1) k = 1;
    // merge 4 sorted asc (cost,ci) lists -> mark k smallest
    int q[4] = {0, 0, 0, 0};
    for (int it = 0; it < k; ++it) {
      float bv = 3.3e38f; int bi = 0x7fffffff; int sel = -1;
#pragma unroll
      for (int w = 0; w < 4; ++w) {
        if (q[w] < 10) {
          float v = s_wc[w * 10 + q[w]];
          int   i = s_wi[w * 10 + q[w]];
          if (v < bv || (v == bv && i < bi)) { bv = v; bi = i; sel = w; }
        }
      }
      if (sel < 0 || bv >= 1e37f) break;   // exhausted real candidates
      atomicOr(&match_c[bo + bi], 1u << g);
      ++q[sel];
    }
    // per-image ticket
    __threadfence();
    s_flag = (atomicAdd(&done_g[b], 1) == NG - 1) ? 1 : 0;
  }
  __syncthreads();
  if (!s_flag) return;

  // ---- finalize (winner block of image b) — packed tables only, no gathers ----
  float li = 0.0f, oe = 0.0f, lc = 0.0f, nf = 0.0f;
  for (int ci = tid; ci < n; ci += 256) {
    unsigned int m = atomicOr(&match_c[bo + ci], 0u);   // coherence-point read
    if (m == 0u) continue;
    float4 me = meta_c[bo + ci];
    float4 pb = bbox_c[bo + ci];
    unsigned int am = __float_as_uint(me.z);
    int mg;
    if (m & (m - 1)) {
      float bestc = 3.4e38f; mg = 0;
      for (int gq = 0; gq < NG; ++gq) {
        float xq = x_tbl[((size_t)b * NG + gq) * NAP + ci];
        float iouq;
        float cq = cost_from_x(xq, me.x, me.y, am, gq, s_gt[gq * 5], s_gt[gq * 5 + 1],
                               s_gt[gq * 5 + 2], s_gt[gq * 5 + 3], pb, iouq);
        if (cq < bestc) { bestc = cq; mg = gq; }
      }
    } else {
      mg = __ffs(m) - 1;
    }
    float gx = s_gt[mg * 5], gy = s_gt[mg * 5 + 1];
    float gw = s_gt[mg * 5 + 2], gh = s_gt[mg * 5 + 3];
    float piou = iou_raw(gx, gy, gw, gh, pb);
    li += giou_loss(pb, gx, gy, gw, gh);
    float xcls = x_tbl[((size_t)b * NG + mg) * NAP + ci];
    lc += sb_c[bo + ci] - xcls * piou;   // bce(x,t) = bce(x,0) - x*t
    oe += me.w;                          // obj logit: bce(x,1) = bce(x,0) - x
    nf += 1.0f;
  }

  float vals[4] = {li, oe, lc, nf};
#pragma unroll
  for (int q2 = 0; q2 < 4; ++q2) {
#pragma unroll
    for (int off = 32; off; off >>= 1) vals[q2] += __shfl_down(vals[q2], off, 64);
  }
  if (lane == 0) {
    s_red[wid * 4 + 0] = vals[0];
    s_red[wid * 4 + 1] = vals[1];
    s_red[wid * 4 + 2] = vals[2];
    s_red[wid * 4 + 3] = vals[3];
  }
  __syncthreads();
  if (tid < 4) {
    const int slot[4] = {0, 2, 3, 4};
    float s = s_red[tid] + s_red[4 + tid] + s_red[8 + tid] + s_red[12 + tid];
    atomicAdd(&accum[slot[tid]], s);
  }

  // ---- final ticket: last image's finalize block emits the scalar ----
  if (tid == 0) {
    __threadfence();
    s_flag = (atomicAdd(done_img, 1) == NB - 1) ? 1 : 0;
  }
  __syncthreads();
  if (!s_flag) return;

  float s = 0.0f;
  for (int i = tid; i < NB * NBLK; i += 256) s += blk_obj[i];  // obj-BCE base
#pragma unroll
  for (int off = 32; off; off >>= 1) s += __shfl_down(s, off, 64);
  if ((tid & 63) == 0) s_red[tid >> 6] = s;
  __syncthreads();
  if (tid == 0) {
    float obj_base = s_red[0] + s_red[1] + s_red[2] + s_red[3];
    float loss_iou = atomicAdd(&accum[0], 0.0f);   // coherent read-backs
    float oex      = atomicAdd(&accum[2], 0.0f);
    float loss_cls = atomicAdd(&accum[3], 0.0f);
    float num_fg   = atomicAdd(&accum[4], 0.0f);
    float loss_obj = obj_base - oex;
    out[0] = (5.0f * loss_iou + loss_obj + loss_cls) / fmaxf(num_fg, 1.0f);
  }
}

// ---------- launch ----------
extern "C" void kernel_launch(void* const* d_in, const int* in_sizes, int n_in,
                              void* d_out, int out_size, void* d_ws, size_t ws_size,
                              hipStream_t stream) {
  const float* p8     = (const float*)d_in[0];
  const float* p16    = (const float*)d_in[1];
  const float* p32    = (const float*)d_in[2];
  const float* labels = (const float*)d_in[3];
  float* out = (float*)d_out;

  const size_t BAP = (size_t)NB * NAP;     // 270336
  char* w = (char*)d_ws;
  float4*       bbox_c   = (float4*)w;                             // 4.33 MB, 16B-aligned
  float4*       meta_c   = (float4*)(w + BAP * 16);                // 4.33 MB
  float*        x_tbl    = (float*)(w + BAP * 32);                 // NB*NG*NAP*4 = 21.6 MB
  char*         w2       = (char*)x_tbl + (size_t)NB * NG * NAP * 4;
  float*        sb_c     = (float*)(w2);
  unsigned int* match_c  = (unsigned int*)(w2 + BAP * 4);
  char*         w3       = w2 + BAP * 8;
  // zeroed region (512 B): n_fg(32i)@0, accum(8f)@128, done_g(32i)@256, done_img@384
  int*          n_fg     = (int*)w3;
  float*        accum    = (float*)(w3 + 128);
  int*          done_g   = (int*)(w3 + 256);
  int*          done_img = (int*)(w3 + 384);
  float*        blk_obj  = (float*)(w3 + 512);                     // NB*NBLK floats (4224 B)

  hipMemsetAsync(w3, 0, 512, stream);

  kA <<<dim3(NBLK, NB), dim3(256), 0, stream>>>(p8, p16, p32, labels, n_fg, meta_c,
                                                bbox_c, sb_c, x_tbl, match_c, blk_obj);
  kBG<<<dim3(NG, NB), dim3(256), 0, stream>>>(labels, n_fg, meta_c, bbox_c, sb_c, x_tbl,
                                              match_c, blk_obj, accum, done_g,
                                              done_img, out);
}